// Round 8
// baseline (32.922 us; speedup 1.0000x reference)
//
#include <hip/hip_runtime.h>

#define BB 8
#define SS 4096
#define DD 64
#define NH 8
#define NBKT 64
#define OUT_V_ELEMS (BB*SS*DD)   // 2097152 floats of o, then buckets (BB*NH*SS floats)

typedef float sf4 __attribute__((ext_vector_type(4)));

// Grid: 512 blocks = (B*S)/64 tokens. Block: 256 thr = 4 waves.
// Lane owns ONE rot column d = wave*64 + lane (hash h = d>>5, col c = d&31),
// held in 64 VGPRs. q[t,f] is wave-uniform -> streamed through SGPRs via
// inline-asm s_load_dwordx4; v_fma_f32 reads the scalar operand directly, so
// the inner loop has ZERO vector-memory traffic. Dots transposed through LDS
// for the per-token argmax epilogue.
__global__ __launch_bounds__(256, 2) void lsh_hash_kernel(
    const float* __restrict__ qk,
    const float* __restrict__ v,
    const float* __restrict__ rot,
    float* __restrict__ out)
{
    __shared__ float dots_s[64 * 256];   // 64 KB: [token][dir]

    const int tid  = threadIdx.x;
    const int blk  = blockIdx.x;
    const int b    = blk >> 6;           // 0..7
    const int t0   = (blk & 63) * 64;    // token base
    const int lane = tid & 63;
    const int w    = tid >> 6;           // wave = dir quad
    const int d    = w * 64 + lane;      // global dir column 0..255

    // ---- fused v -> out[0] copy (output 0 == v exactly; self-mask keeps only t==t) ----
    {
        const float4* v4 = (const float4*)v;
        float4*       o4 = (float4*)out;
        const int base = blk * 1024 + tid;
#pragma unroll
        for (int jj = 0; jj < 4; ++jj)
            o4[base + jj * 256] = v4[base + jj * 256];
    }

    // ---- rot column preload: 64 VGPRs/lane, coalesced per-f (lanes consecutive) ----
    float rot_reg[64];
#pragma unroll
    for (int f = 0; f < 64; ++f)
        rot_reg[f] = rot[f * 256 + d];

    const float* qbase = qk + (size_t)(b * SS + t0) * 64;

#define ISSUE1(qv, j, fbv)                                                   \
    asm volatile("s_load_dwordx4 %0, %1, %2"                                 \
                 : "=s"(qv) : "s"(ptg), "i"((j) * 256 + (fbv) * 16))
#define ISSUE8(S, fbv)                                                       \
    ISSUE1(S##0, 0, fbv); ISSUE1(S##1, 1, fbv); ISSUE1(S##2, 2, fbv);        \
    ISSUE1(S##3, 3, fbv); ISSUE1(S##4, 4, fbv); ISSUE1(S##5, 5, fbv);        \
    ISSUE1(S##6, 6, fbv); ISSUE1(S##7, 7, fbv)
#define WAIT8(S)                                                             \
    asm volatile("s_waitcnt lgkmcnt(0)"                                      \
                 : "+s"(S##0), "+s"(S##1), "+s"(S##2), "+s"(S##3),           \
                   "+s"(S##4), "+s"(S##5), "+s"(S##6), "+s"(S##7))
#define FMA4(qv, j, fbv)                                                     \
    acc[j] = fmaf(qv[0], rot_reg[(fbv)*4+0], acc[j]);                        \
    acc[j] = fmaf(qv[1], rot_reg[(fbv)*4+1], acc[j]);                        \
    acc[j] = fmaf(qv[2], rot_reg[(fbv)*4+2], acc[j]);                        \
    acc[j] = fmaf(qv[3], rot_reg[(fbv)*4+3], acc[j])
#define FMA32(S, fbv)                                                        \
    FMA4(S##0, 0, fbv); FMA4(S##1, 1, fbv); FMA4(S##2, 2, fbv);              \
    FMA4(S##3, 3, fbv); FMA4(S##4, 4, fbv); FMA4(S##5, 5, fbv);              \
    FMA4(S##6, 6, fbv); FMA4(S##7, 7, fbv)
// wait for CUR (covered by prev step's FMAs), issue NXT, consume CUR
#define STEP(fbv, CUR, NXT)                                                  \
    WAIT8(CUR);                                                              \
    if ((fbv) < 15) { ISSUE8(NXT, (fbv) + 1); }                              \
    FMA32(CUR, fbv)

#pragma unroll 1
    for (int tg = 0; tg < 8; ++tg) {
        const float* ptg = qbase + tg * 512;   // uniform -> SGPR pair
        float acc[8];
#pragma unroll
        for (int j = 0; j < 8; ++j) acc[j] = 0.0f;

        sf4 qA0, qA1, qA2, qA3, qA4, qA5, qA6, qA7;
        sf4 qB0, qB1, qB2, qB3, qB4, qB5, qB6, qB7;
        ISSUE8(qA, 0);
        STEP(0,  qA, qB); STEP(1,  qB, qA); STEP(2,  qA, qB); STEP(3,  qB, qA);
        STEP(4,  qA, qB); STEP(5,  qB, qA); STEP(6,  qA, qB); STEP(7,  qB, qA);
        STEP(8,  qA, qB); STEP(9,  qB, qA); STEP(10, qA, qB); STEP(11, qB, qA);
        STEP(12, qA, qB); STEP(13, qB, qA); STEP(14, qA, qB); STEP(15, qB, qA);

        // transpose: dots_s[token][dir] (lanes consecutive -> conflict-free)
#pragma unroll
        for (int j = 0; j < 8; ++j)
            dots_s[(tg * 8 + j) * 256 + d] = acc[j];
    }
#undef STEP
#undef FMA32
#undef FMA4
#undef WAIT8
#undef ISSUE8
#undef ISSUE1

    __syncthreads();

    // ---- argmax epilogue: lane -> (token t, hash pair) ----
    const int t  = tid >> 2;
    const int hh = tid & 3;
#pragma unroll
    for (int k = 0; k < 2; ++k) {
        const int h = hh * 2 + k;
        float pv = -1e30f; int pi = 0;
        float nv = -1e30f; int ni = 0;
#pragma unroll
        for (int j = 0; j < 8; ++j) {
            const int cj = (j + t) & 7;     // rotated chunk order (bank spread)
            const float4 x = *(const float4*)&dots_s[t * 256 + h * 32 + cj * 4];
            const float xv[4] = {x.x, x.y, x.z, x.w};
#pragma unroll
            for (int e = 0; e < 4; ++e) {
                const float val = xv[e];
                const int   col = cj * 4 + e;
                if (val > pv || (val == pv && col < pi)) { pv = val; pi = col; }
                const float nval = -val;
                if (nval > nv || (nval == nv && col < ni)) { nv = nval; ni = col; }
            }
        }
        const int idx = (pv >= nv) ? pi : (ni + 32);   // positive half wins ties
        out[OUT_V_ELEMS + b * (NH * SS) + h * SS + t0 + t] = (float)(idx + h * NBKT);
    }
}

extern "C" void kernel_launch(void* const* d_in, const int* in_sizes, int n_in,
                              void* d_out, int out_size, void* d_ws, size_t ws_size,
                              hipStream_t stream) {
    const float* qk  = (const float*)d_in[0];
    const float* v   = (const float*)d_in[1];
    const float* rot = (const float*)d_in[2];
    float* out = (float*)d_out;
    hipLaunchKernelGGL(lsh_hash_kernel, dim3(512), dim3(256), 0, stream,
                       qk, v, rot, out);
}